// Round 14
// baseline (333.824 us; speedup 1.0000x reference)
//
#include <hip/hip_runtime.h>
#include <math.h>

#define S_LEN 2048
#define DH 64
#define BH_N 64
#define BQ 128
#define KT 64

typedef __attribute__((ext_vector_type(8))) short bf16x8;
typedef __attribute__((ext_vector_type(4))) float f32x4;
typedef __attribute__((ext_vector_type(4))) short s16x4;

__device__ __forceinline__ unsigned short f2bf(float f) {
  unsigned int u = __float_as_uint(f);
  u += 0x7fffu + ((u >> 16) & 1u);
  return (unsigned short)(u >> 16);
}

__device__ __forceinline__ unsigned cvt_pk(float lo, float hi) {
  unsigned r;
  asm("v_cvt_pk_bf16_f32 %0, %1, %2" : "=v"(r) : "v"(lo), "v"(hi));
  return r;
}

// R11 base (XCD swizzle + nt scalar burst-ordered stores + ldsW PV path).
// Change: ldsK REMOVED -- K fragments load directly from global (L2-resident
// via XCD swizzle; 16B/lane contiguous, R1-validated A/B mapping). Freed
// 16KB lets 4-tile groups fit in 48KB (3 blocks/CU): barriers 32 -> 16,
// stage phase halves (V only), K loads overlap compute.
__global__ __launch_bounds__(256, 2)
void curve_attn_kernel(const float* __restrict__ Qg,
                       const float* __restrict__ Kg,
                       const float* __restrict__ Vg,
                       float* __restrict__ Og,
                       float* __restrict__ Wg,
                       float sc_l2e, float neg_l2C)
{
  __shared__ unsigned short ldsV[4][64 * 64];   // [tile][d][k_local], swizzled
  __shared__ unsigned short ldsW[4][32 * 64];   // per-wave [q_local][k_local], swizzled

  const int tid  = threadIdx.x;
  const int lane = tid & 63;
  const int wv   = tid >> 6;
  const int lr   = lane & 15;
  const int lg   = lane >> 4;

  // XCD-aware swizzle (nwg = 1024, 8 XCDs, 128 blocks per XCD chunk)
  const int bid = (blockIdx.x & 7) * 128 + (blockIdx.x >> 3);
  const int bh  = bid >> 4;
  const int qt  = (bid & 15) * BQ;

  const size_t sd = (size_t)S_LEN * DH;
  const float* Qb = Qg + (size_t)bh * sd;
  const float* Kb = Kg + (size_t)bh * sd;
  const float* Vb = Vg + (size_t)bh * sd;
  float* Ob = Og + (size_t)bh * sd;
  float* Wb = Wg + (size_t)bh * (size_t)S_LEN * S_LEN;

  const int qrow0 = qt + wv * 32;

  // ---- Q fragments (R1 verbatim): A-frag m=lr, k=8*lg+i ----
  bf16x8 qf[2][2];
#pragma unroll
  for (int mb = 0; mb < 2; ++mb)
#pragma unroll
    for (int kb = 0; kb < 2; ++kb) {
      const float* src = Qb + (size_t)(qrow0 + mb * 16 + lr) * DH + kb * 32 + lg * 8;
      float4 a = *(const float4*)src;
      float4 b = *(const float4*)(src + 4);
      bf16x8 q;
      q[0] = (short)f2bf(a.x); q[1] = (short)f2bf(a.y);
      q[2] = (short)f2bf(a.z); q[3] = (short)f2bf(a.w);
      q[4] = (short)f2bf(b.x); q[5] = (short)f2bf(b.y);
      q[6] = (short)f2bf(b.z); q[7] = (short)f2bf(b.w);
      qf[mb][kb] = q;
    }

  f32x4 oacc[2][4];
#pragma unroll
  for (int i = 0; i < 2; ++i)
#pragma unroll
    for (int j = 0; j < 4; ++j)
      oacc[i][j] = (f32x4){0.f, 0.f, 0.f, 0.f};

  // V staging thread mapping (R1 verbatim)
  const int vr = (tid >> 4) * 4;    // V k-row quad base
  const int vc = (tid & 15) * 4;    // V d-col quad base

  auto stage_v = [&](int t0, int buf) {
    float4 vv[4];
    const float* src = Vb + (size_t)(t0 + vr) * DH + vc;
#pragma unroll
    for (int jr = 0; jr < 4; ++jr)
      vv[jr] = *(const float4*)(src + jr * DH);
#pragma unroll
    for (int jj = 0; jj < 4; ++jj) {
      int row = vc + jj;            // d index
      int e   = row * 64 + vr;      // col = k index
      int se  = e ^ ((row & 7) << 3);
      s16x4 p;
      p[0] = (short)f2bf(((const float*)&vv[0])[jj]);
      p[1] = (short)f2bf(((const float*)&vv[1])[jj]);
      p[2] = (short)f2bf(((const float*)&vv[2])[jj]);
      p[3] = (short)f2bf(((const float*)&vv[3])[jj]);
      *(s16x4*)&ldsV[buf][se] = p;
    }
  };

  auto compute = [&](int buf, int kt) {
    // ---- QK^T: A=Q, B=K -> C[m=q][n=k]; K frags DIRECT from global/L2 ----
    f32x4 sacc[2][4];
#pragma unroll
    for (int i = 0; i < 2; ++i)
#pragma unroll
      for (int j = 0; j < 4; ++j)
        sacc[i][j] = (f32x4){0.f, 0.f, 0.f, 0.f};

#pragma unroll
    for (int db = 0; db < 2; ++db) {
      bf16x8 kf[4];
#pragma unroll
      for (int nb = 0; nb < 4; ++nb) {
        // B-frag: n = nb*16+lr (k row), kdim = db*32 + lg*8 + i
        const float* src = Kb + (size_t)(kt + nb * 16 + lr) * DH + db * 32 + lg * 8;
        float4 a = *(const float4*)src;
        float4 b = *(const float4*)(src + 4);
        union { unsigned u[4]; bf16x8 v; } p;
        p.u[0] = cvt_pk(a.x, a.y); p.u[1] = cvt_pk(a.z, a.w);
        p.u[2] = cvt_pk(b.x, b.y); p.u[3] = cvt_pk(b.z, b.w);
        kf[nb] = p.v;
      }
#pragma unroll
      for (int mb = 0; mb < 2; ++mb)
#pragma unroll
        for (int nb = 0; nb < 4; ++nb)
          sacc[mb][nb] = __builtin_amdgcn_mfma_f32_16x16x32_bf16(
              qf[mb][db], kf[nb], sacc[mb][nb], 0, 0, 0);
    }

    // ---- epilogue (R11 verbatim): exp; nt scalar stores nb-inner; ldsW ----
#pragma unroll
    for (int mb = 0; mb < 2; ++mb) {
      float wvv[4][4];                      // [nb][r]
#pragma unroll
      for (int nb = 0; nb < 4; ++nb)
#pragma unroll
        for (int r = 0; r < 4; ++r)
          wvv[nb][r] = exp2f(sacc[mb][nb][r] * sc_l2e + neg_l2C);

      float* base = Wb + (size_t)(qrow0 + mb * 16 + lg * 4) * S_LEN + kt + lr;
#pragma unroll
      for (int r = 0; r < 4; ++r)
#pragma unroll
        for (int nb = 0; nb < 4; ++nb)
          __builtin_nontemporal_store(wvv[nb][r],
                                      base + (size_t)r * S_LEN + nb * 16);

#pragma unroll
      for (int nb = 0; nb < 4; ++nb)
#pragma unroll
        for (int r = 0; r < 4; ++r) {
          int row = mb * 16 + lg * 4 + r;
          int e   = (row * 64 + nb * 16 + lr) ^ ((row & 7) << 3);
          ldsW[wv][e] = f2bf(wvv[nb][r]);
        }
    }

    // ---- PV (R11 verbatim): A=W, B=V -> C[m=q][n=d] ----
#pragma unroll
    for (int kb = 0; kb < 2; ++kb) {
      bf16x8 af[2];
#pragma unroll
      for (int mb = 0; mb < 2; ++mb) {
        int row = mb * 16 + lr;
        int e   = (row * 64 + kb * 32 + lg * 8) ^ ((row & 7) << 3);
        af[mb] = *(const bf16x8*)&ldsW[wv][e];
      }
#pragma unroll
      for (int db = 0; db < 4; ++db) {
        int row = db * 16 + lr;
        int e   = (row * 64 + kb * 32 + lg * 8) ^ ((row & 7) << 3);
        bf16x8 vf = *(const bf16x8*)&ldsV[buf][e];
#pragma unroll
        for (int mb = 0; mb < 2; ++mb)
          oacc[mb][db] = __builtin_amdgcn_mfma_f32_16x16x32_bf16(
              af[mb], vf, oacc[mb][db], 0, 0, 0);
      }
    }
  };

  // ---- main loop: 4-tile groups (16 barriers total), V-only staging ----
#pragma unroll 1
  for (int kt = 0; kt < S_LEN; kt += 4 * KT) {
    __syncthreads();            // protect ldsV from previous group's readers
    stage_v(kt, 0);
    stage_v(kt + KT, 1);
    stage_v(kt + 2 * KT, 2);
    stage_v(kt + 3 * KT, 3);
    __syncthreads();
    compute(0, kt);
    compute(1, kt + KT);
    compute(2, kt + 2 * KT);
    compute(3, kt + 3 * KT);
  }

  // ---- write O (nt, R11 verbatim) ----
#pragma unroll
  for (int mb = 0; mb < 2; ++mb)
#pragma unroll
    for (int db = 0; db < 4; ++db) {
      float* dst = Ob + (size_t)(qrow0 + mb * 16 + lg * 4) * DH + db * 16 + lr;
#pragma unroll
      for (int r = 0; r < 4; ++r)
        __builtin_nontemporal_store(oacc[mb][db][r], dst + (size_t)r * DH);
    }
}

extern "C" void kernel_launch(void* const* d_in, const int* in_sizes, int n_in,
                              void* d_out, int out_size, void* d_ws, size_t ws_size,
                              hipStream_t stream) {
  const float* Q = (const float*)d_in[0];
  const float* K = (const float*)d_in[1];
  const float* V = (const float*)d_in[2];
  float* O = (float*)d_out;
  float* W = O + (size_t)BH_N * S_LEN * DH;

  const double E = 2.718281828459045235360287;
  double C = 1.0 + exp(E);
  float neg_l2C = (float)(-(log(C) / log(2.0)));
  float sc_l2e  = (float)(0.125 / log(2.0));

  curve_attn_kernel<<<dim3(BH_N * (S_LEN / BQ)), dim3(256), 0, stream>>>(
      Q, K, V, O, W, sc_l2e, neg_l2C);
}

// Round 15
// 250.754 us; speedup vs baseline: 1.3313x; 1.3313x over previous
//
#include <hip/hip_runtime.h>
#include <math.h>

#define S_LEN 2048
#define DH 64
#define BH_N 64
#define BQ 128
#define KT 64
#define NT (S_LEN / KT)

typedef __attribute__((ext_vector_type(8))) short bf16x8;
typedef __attribute__((ext_vector_type(4))) float f32x4;
typedef __attribute__((ext_vector_type(4))) short s16x4;

__device__ __forceinline__ unsigned short f2bf(float f) {
  unsigned int u = __float_as_uint(f);
  u += 0x7fffu + ((u >> 16) & 1u);
  return (unsigned short)(u >> 16);
}

// R11 base (XCD swizzle + nt burst-ordered scalar stores + ldsK/ldsV/ldsW).
// Change: double-buffered OVERLAP schedule -- stage(t+1) is issued at the
// top of each iteration so its global loads stream during compute(t); one
// __syncthreads per tile (same barrier count as R11, but the dedicated
// stage-stall phase is gone). Buffers disjoint: stage->1^(t&1), compute->t&1.
__global__ __launch_bounds__(256, 2)
void curve_attn_kernel(const float* __restrict__ Qg,
                       const float* __restrict__ Kg,
                       const float* __restrict__ Vg,
                       float* __restrict__ Og,
                       float* __restrict__ Wg,
                       float sc_l2e, float neg_l2C)
{
  __shared__ unsigned short ldsK[2][64 * 64];   // [buf][k_local][d], swizzled
  __shared__ unsigned short ldsV[2][64 * 64];   // [buf][d][k_local], swizzled
  __shared__ unsigned short ldsW[4][32 * 64];   // per-wave [q_local][k_local], swizzled

  const int tid  = threadIdx.x;
  const int lane = tid & 63;
  const int wv   = tid >> 6;
  const int lr   = lane & 15;
  const int lg   = lane >> 4;

  // XCD-aware swizzle (nwg = 1024, 8 XCDs, 128 blocks per XCD chunk)
  const int bid = (blockIdx.x & 7) * 128 + (blockIdx.x >> 3);
  const int bh  = bid >> 4;
  const int qt  = (bid & 15) * BQ;

  const size_t sd = (size_t)S_LEN * DH;
  const float* Qb = Qg + (size_t)bh * sd;
  const float* Kb = Kg + (size_t)bh * sd;
  const float* Vb = Vg + (size_t)bh * sd;
  float* Ob = Og + (size_t)bh * sd;
  float* Wb = Wg + (size_t)bh * (size_t)S_LEN * S_LEN;

  const int qrow0 = qt + wv * 32;

  // ---- Q fragments (R1 verbatim): A-frag m=lr, k=8*lg+i ----
  bf16x8 qf[2][2];
#pragma unroll
  for (int mb = 0; mb < 2; ++mb)
#pragma unroll
    for (int kb = 0; kb < 2; ++kb) {
      const float* src = Qb + (size_t)(qrow0 + mb * 16 + lr) * DH + kb * 32 + lg * 8;
      float4 a = *(const float4*)src;
      float4 b = *(const float4*)(src + 4);
      bf16x8 q;
      q[0] = (short)f2bf(a.x); q[1] = (short)f2bf(a.y);
      q[2] = (short)f2bf(a.z); q[3] = (short)f2bf(a.w);
      q[4] = (short)f2bf(b.x); q[5] = (short)f2bf(b.y);
      q[6] = (short)f2bf(b.z); q[7] = (short)f2bf(b.w);
      qf[mb][kb] = q;
    }

  f32x4 oacc[2][4];
#pragma unroll
  for (int i = 0; i < 2; ++i)
#pragma unroll
    for (int j = 0; j < 4; ++j)
      oacc[i][j] = (f32x4){0.f, 0.f, 0.f, 0.f};

  // staging thread mapping (R1 verbatim)
  const int kr = tid >> 2;          // K row 0..63
  const int kc = (tid & 3) * 4;     // K col base {0,4,8,12}
  const int vr = (tid >> 4) * 4;    // V k-row quad base
  const int vc = (tid & 15) * 4;    // V d-col quad base

  auto stage = [&](int t0, int buf) {
    // K tile
    {
      const float* src = Kb + (size_t)(t0 + kr) * DH + kc;
#pragma unroll
      for (int j = 0; j < 4; ++j) {
        float4 v = *(const float4*)(src + 16 * j);
        int e  = kr * 64 + kc + 16 * j;
        int se = e ^ ((kr & 7) << 3);
        s16x4 p;
        p[0] = (short)f2bf(v.x); p[1] = (short)f2bf(v.y);
        p[2] = (short)f2bf(v.z); p[3] = (short)f2bf(v.w);
        *(s16x4*)&ldsK[buf][se] = p;
      }
    }
    // V tile (transposed)
    {
      float4 vv[4];
      const float* src = Vb + (size_t)(t0 + vr) * DH + vc;
#pragma unroll
      for (int jr = 0; jr < 4; ++jr)
        vv[jr] = *(const float4*)(src + jr * DH);
#pragma unroll
      for (int jj = 0; jj < 4; ++jj) {
        int row = vc + jj;            // d index
        int e   = row * 64 + vr;      // col = k index
        int se  = e ^ ((row & 7) << 3);
        s16x4 p;
        p[0] = (short)f2bf(((const float*)&vv[0])[jj]);
        p[1] = (short)f2bf(((const float*)&vv[1])[jj]);
        p[2] = (short)f2bf(((const float*)&vv[2])[jj]);
        p[3] = (short)f2bf(((const float*)&vv[3])[jj]);
        *(s16x4*)&ldsV[buf][se] = p;
      }
    }
  };

  auto compute = [&](int buf, int kt) {
    // ---- QK^T (R11 verbatim): A=Q, B=K -> C[m=q][n=k] ----
    f32x4 sacc[2][4];
#pragma unroll
    for (int i = 0; i < 2; ++i)
#pragma unroll
      for (int j = 0; j < 4; ++j)
        sacc[i][j] = (f32x4){0.f, 0.f, 0.f, 0.f};

#pragma unroll
    for (int db = 0; db < 2; ++db) {
      bf16x8 kf[4];
#pragma unroll
      for (int nb = 0; nb < 4; ++nb) {
        int row = nb * 16 + lr;
        int e   = (row * 64 + db * 32 + lg * 8) ^ ((row & 7) << 3);
        kf[nb] = *(const bf16x8*)&ldsK[buf][e];
      }
#pragma unroll
      for (int mb = 0; mb < 2; ++mb)
#pragma unroll
        for (int nb = 0; nb < 4; ++nb)
          sacc[mb][nb] = __builtin_amdgcn_mfma_f32_16x16x32_bf16(
              qf[mb][db], kf[nb], sacc[mb][nb], 0, 0, 0);
    }

    // ---- epilogue (R11 verbatim): exp; nt stores nb-inner; ldsW ----
#pragma unroll
    for (int mb = 0; mb < 2; ++mb) {
      float wvv[4][4];                      // [nb][r]
#pragma unroll
      for (int nb = 0; nb < 4; ++nb)
#pragma unroll
        for (int r = 0; r < 4; ++r)
          wvv[nb][r] = exp2f(sacc[mb][nb][r] * sc_l2e + neg_l2C);

      float* base = Wb + (size_t)(qrow0 + mb * 16 + lg * 4) * S_LEN + kt + lr;
#pragma unroll
      for (int r = 0; r < 4; ++r)
#pragma unroll
        for (int nb = 0; nb < 4; ++nb)
          __builtin_nontemporal_store(wvv[nb][r],
                                      base + (size_t)r * S_LEN + nb * 16);

#pragma unroll
      for (int nb = 0; nb < 4; ++nb)
#pragma unroll
        for (int r = 0; r < 4; ++r) {
          int row = mb * 16 + lg * 4 + r;
          int e   = (row * 64 + nb * 16 + lr) ^ ((row & 7) << 3);
          ldsW[wv][e] = f2bf(wvv[nb][r]);
        }
    }

    // ---- PV (R11 verbatim): A=W, B=V -> C[m=q][n=d] ----
#pragma unroll
    for (int kb = 0; kb < 2; ++kb) {
      bf16x8 af[2];
#pragma unroll
      for (int mb = 0; mb < 2; ++mb) {
        int row = mb * 16 + lr;
        int e   = (row * 64 + kb * 32 + lg * 8) ^ ((row & 7) << 3);
        af[mb] = *(const bf16x8*)&ldsW[wv][e];
      }
#pragma unroll
      for (int db = 0; db < 4; ++db) {
        int row = db * 16 + lr;
        int e   = (row * 64 + kb * 32 + lg * 8) ^ ((row & 7) << 3);
        bf16x8 vf = *(const bf16x8*)&ldsV[buf][e];
#pragma unroll
        for (int mb = 0; mb < 2; ++mb)
          oacc[mb][db] = __builtin_amdgcn_mfma_f32_16x16x32_bf16(
              af[mb], vf, oacc[mb][db], 0, 0, 0);
      }
    }
  };

  // ---- pipeline: stage(t+1) overlaps compute(t); 1 barrier per tile ----
  stage(0, 0);
  __syncthreads();

#pragma unroll 1
  for (int t = 0; t < NT; ++t) {
    if (t + 1 < NT)
      stage((t + 1) * KT, (t + 1) & 1);   // loads stream under compute(t)
    compute(t & 1, t * KT);
    __syncthreads();                      // publishes buf (t+1)&1, protects t&1
  }

  // ---- write O (nt, R11 verbatim) ----
#pragma unroll
  for (int mb = 0; mb < 2; ++mb)
#pragma unroll
    for (int db = 0; db < 4; ++db) {
      float* dst = Ob + (size_t)(qrow0 + mb * 16 + lg * 4) * DH + db * 16 + lr;
#pragma unroll
      for (int r = 0; r < 4; ++r)
        __builtin_nontemporal_store(oacc[mb][db][r], dst + (size_t)r * DH);
    }
}

extern "C" void kernel_launch(void* const* d_in, const int* in_sizes, int n_in,
                              void* d_out, int out_size, void* d_ws, size_t ws_size,
                              hipStream_t stream) {
  const float* Q = (const float*)d_in[0];
  const float* K = (const float*)d_in[1];
  const float* V = (const float*)d_in[2];
  float* O = (float*)d_out;
  float* W = O + (size_t)BH_N * S_LEN * DH;

  const double E = 2.718281828459045235360287;
  double C = 1.0 + exp(E);
  float neg_l2C = (float)(-(log(C) / log(2.0)));
  float sc_l2e  = (float)(0.125 / log(2.0));

  curve_attn_kernel<<<dim3(BH_N * (S_LEN / BQ)), dim3(256), 0, stream>>>(
      Q, K, V, O, W, sc_l2e, neg_l2C);
}

// Round 16
// 233.566 us; speedup vs baseline: 1.4292x; 1.0736x over previous
//
#include <hip/hip_runtime.h>
#include <math.h>

#define S_LEN 2048
#define DH 64
#define BH_N 64
#define BQ 128
#define KT 64
#define NT (S_LEN / KT)

typedef __attribute__((ext_vector_type(8))) short bf16x8;
typedef __attribute__((ext_vector_type(4))) float f32x4;
typedef __attribute__((ext_vector_type(4))) short s16x4;

__device__ __forceinline__ unsigned short f2bf(float f) {
  unsigned int u = __float_as_uint(f);
  u += 0x7fffu + ((u >> 16) & 1u);
  return (unsigned short)(u >> 16);
}

// lgkm-only barrier (correctness-validated in R4): publishes LDS writes,
// does NOT drain vmcnt -> nt stores stream across tile boundaries.
__device__ __forceinline__ void lgkm_barrier() {
  __builtin_amdgcn_sched_barrier(0);
  asm volatile("s_waitcnt lgkmcnt(0)\n\ts_barrier" ::: "memory");
  __builtin_amdgcn_sched_barrier(0);
}

// R15 base (XCD swizzle + nt burst-ordered stores + dbuf overlap). Changes:
// T14 split staging -- load_regs(t+1) issued at TOP (fire-and-forget),
// cvt_write(t+1) AFTER compute(t): the ds_writes wait only on the 8 loads
// (vmcnt in-order: 32 younger epilogue stores may remain in flight), and the
// lgkm-only barrier never drains the nt store queue. +32 VGPR prefetch state.
__global__ __launch_bounds__(256, 2)
void curve_attn_kernel(const float* __restrict__ Qg,
                       const float* __restrict__ Kg,
                       const float* __restrict__ Vg,
                       float* __restrict__ Og,
                       float* __restrict__ Wg,
                       float sc_l2e, float neg_l2C)
{
  __shared__ unsigned short ldsK[2][64 * 64];   // [buf][k_local][d], swizzled
  __shared__ unsigned short ldsV[2][64 * 64];   // [buf][d][k_local], swizzled
  __shared__ unsigned short ldsW[4][32 * 64];   // per-wave [q_local][k_local], swizzled

  const int tid  = threadIdx.x;
  const int lane = tid & 63;
  const int wv   = tid >> 6;
  const int lr   = lane & 15;
  const int lg   = lane >> 4;

  // XCD-aware swizzle (nwg = 1024, 8 XCDs, 128 blocks per XCD chunk)
  const int bid = (blockIdx.x & 7) * 128 + (blockIdx.x >> 3);
  const int bh  = bid >> 4;
  const int qt  = (bid & 15) * BQ;

  const size_t sd = (size_t)S_LEN * DH;
  const float* Qb = Qg + (size_t)bh * sd;
  const float* Kb = Kg + (size_t)bh * sd;
  const float* Vb = Vg + (size_t)bh * sd;
  float* Ob = Og + (size_t)bh * sd;
  float* Wb = Wg + (size_t)bh * (size_t)S_LEN * S_LEN;

  const int qrow0 = qt + wv * 32;

  // ---- Q fragments (R1 verbatim): A-frag m=lr, k=8*lg+i ----
  bf16x8 qf[2][2];
#pragma unroll
  for (int mb = 0; mb < 2; ++mb)
#pragma unroll
    for (int kb = 0; kb < 2; ++kb) {
      const float* src = Qb + (size_t)(qrow0 + mb * 16 + lr) * DH + kb * 32 + lg * 8;
      float4 a = *(const float4*)src;
      float4 b = *(const float4*)(src + 4);
      bf16x8 q;
      q[0] = (short)f2bf(a.x); q[1] = (short)f2bf(a.y);
      q[2] = (short)f2bf(a.z); q[3] = (short)f2bf(a.w);
      q[4] = (short)f2bf(b.x); q[5] = (short)f2bf(b.y);
      q[6] = (short)f2bf(b.z); q[7] = (short)f2bf(b.w);
      qf[mb][kb] = q;
    }

  f32x4 oacc[2][4];
#pragma unroll
  for (int i = 0; i < 2; ++i)
#pragma unroll
    for (int j = 0; j < 4; ++j)
      oacc[i][j] = (f32x4){0.f, 0.f, 0.f, 0.f};

  // staging thread mapping (R1 verbatim)
  const int kr = tid >> 2;          // K row 0..63
  const int kc = (tid & 3) * 4;     // K col base {0,4,8,12}
  const int vr = (tid >> 4) * 4;    // V k-row quad base
  const int vc = (tid & 15) * 4;    // V d-col quad base

  float4 kreg[4], vreg[4];          // prefetch state (+32 VGPR)

  auto load_regs = [&](int t0) {
    const float* ks = Kb + (size_t)(t0 + kr) * DH + kc;
#pragma unroll
    for (int j = 0; j < 4; ++j) kreg[j] = *(const float4*)(ks + 16 * j);
    const float* vs = Vb + (size_t)(t0 + vr) * DH + vc;
#pragma unroll
    for (int j = 0; j < 4; ++j) vreg[j] = *(const float4*)(vs + (size_t)j * DH);
  };

  auto cvt_write = [&](int buf) {
    // K tile (R1-verbatim addressing)
#pragma unroll
    for (int j = 0; j < 4; ++j) {
      float4 v = kreg[j];
      int e  = kr * 64 + kc + 16 * j;
      int se = e ^ ((kr & 7) << 3);
      s16x4 p;
      p[0] = (short)f2bf(v.x); p[1] = (short)f2bf(v.y);
      p[2] = (short)f2bf(v.z); p[3] = (short)f2bf(v.w);
      *(s16x4*)&ldsK[buf][se] = p;
    }
    // V tile transposed (R1-verbatim addressing)
#pragma unroll
    for (int jj = 0; jj < 4; ++jj) {
      int row = vc + jj;
      int e   = row * 64 + vr;
      int se  = e ^ ((row & 7) << 3);
      s16x4 p;
      p[0] = (short)f2bf(((const float*)&vreg[0])[jj]);
      p[1] = (short)f2bf(((const float*)&vreg[1])[jj]);
      p[2] = (short)f2bf(((const float*)&vreg[2])[jj]);
      p[3] = (short)f2bf(((const float*)&vreg[3])[jj]);
      *(s16x4*)&ldsV[buf][se] = p;
    }
  };

  auto compute = [&](int buf, int kt) {
    // ---- QK^T (R11 verbatim): A=Q, B=K -> C[m=q][n=k] ----
    f32x4 sacc[2][4];
#pragma unroll
    for (int i = 0; i < 2; ++i)
#pragma unroll
      for (int j = 0; j < 4; ++j)
        sacc[i][j] = (f32x4){0.f, 0.f, 0.f, 0.f};

#pragma unroll
    for (int db = 0; db < 2; ++db) {
      bf16x8 kf[4];
#pragma unroll
      for (int nb = 0; nb < 4; ++nb) {
        int row = nb * 16 + lr;
        int e   = (row * 64 + db * 32 + lg * 8) ^ ((row & 7) << 3);
        kf[nb] = *(const bf16x8*)&ldsK[buf][e];
      }
#pragma unroll
      for (int mb = 0; mb < 2; ++mb)
#pragma unroll
        for (int nb = 0; nb < 4; ++nb)
          sacc[mb][nb] = __builtin_amdgcn_mfma_f32_16x16x32_bf16(
              qf[mb][db], kf[nb], sacc[mb][nb], 0, 0, 0);
    }

    // ---- epilogue (R11 verbatim): exp; nt stores nb-inner; ldsW ----
#pragma unroll
    for (int mb = 0; mb < 2; ++mb) {
      float wvv[4][4];                      // [nb][r]
#pragma unroll
      for (int nb = 0; nb < 4; ++nb)
#pragma unroll
        for (int r = 0; r < 4; ++r)
          wvv[nb][r] = exp2f(sacc[mb][nb][r] * sc_l2e + neg_l2C);

      float* base = Wb + (size_t)(qrow0 + mb * 16 + lg * 4) * S_LEN + kt + lr;
#pragma unroll
      for (int r = 0; r < 4; ++r)
#pragma unroll
        for (int nb = 0; nb < 4; ++nb)
          __builtin_nontemporal_store(wvv[nb][r],
                                      base + (size_t)r * S_LEN + nb * 16);

#pragma unroll
      for (int nb = 0; nb < 4; ++nb)
#pragma unroll
        for (int r = 0; r < 4; ++r) {
          int row = mb * 16 + lg * 4 + r;
          int e   = (row * 64 + nb * 16 + lr) ^ ((row & 7) << 3);
          ldsW[wv][e] = f2bf(wvv[nb][r]);
        }
    }

    // ---- PV (R11 verbatim): A=W, B=V -> C[m=q][n=d] ----
#pragma unroll
    for (int kb = 0; kb < 2; ++kb) {
      bf16x8 af[2];
#pragma unroll
      for (int mb = 0; mb < 2; ++mb) {
        int row = mb * 16 + lr;
        int e   = (row * 64 + kb * 32 + lg * 8) ^ ((row & 7) << 3);
        af[mb] = *(const bf16x8*)&ldsW[wv][e];
      }
#pragma unroll
      for (int db = 0; db < 4; ++db) {
        int row = db * 16 + lr;
        int e   = (row * 64 + kb * 32 + lg * 8) ^ ((row & 7) << 3);
        bf16x8 vf = *(const bf16x8*)&ldsV[buf][e];
#pragma unroll
        for (int mb = 0; mb < 2; ++mb)
          oacc[mb][db] = __builtin_amdgcn_mfma_f32_16x16x32_bf16(
              af[mb], vf, oacc[mb][db], 0, 0, 0);
      }
    }
  };

  // ---- pipeline: loads issue-early, LDS write-late, lgkm-only barriers ----
  load_regs(0);
  cvt_write(0);
  lgkm_barrier();

#pragma unroll 1
  for (int t = 0; t < NT; ++t) {
    if (t + 1 < NT)
      load_regs((t + 1) * KT);       // fire-and-forget; lands during compute
    compute(t & 1, t * KT);
    if (t + 1 < NT)
      cvt_write((t + 1) & 1);        // waits loads only (younger stores fly)
    lgkm_barrier();                  // publishes LDS; nt stores keep streaming
  }

  // ---- write O (nt, R11 verbatim) ----
#pragma unroll
  for (int mb = 0; mb < 2; ++mb)
#pragma unroll
    for (int db = 0; db < 4; ++db) {
      float* dst = Ob + (size_t)(qrow0 + mb * 16 + lg * 4) * DH + db * 16 + lr;
#pragma unroll
      for (int r = 0; r < 4; ++r)
        __builtin_nontemporal_store(oacc[mb][db][r], dst + (size_t)r * DH);
    }
}

extern "C" void kernel_launch(void* const* d_in, const int* in_sizes, int n_in,
                              void* d_out, int out_size, void* d_ws, size_t ws_size,
                              hipStream_t stream) {
  const float* Q = (const float*)d_in[0];
  const float* K = (const float*)d_in[1];
  const float* V = (const float*)d_in[2];
  float* O = (float*)d_out;
  float* W = O + (size_t)BH_N * S_LEN * DH;

  const double E = 2.718281828459045235360287;
  double C = 1.0 + exp(E);
  float neg_l2C = (float)(-(log(C) / log(2.0)));
  float sc_l2e  = (float)(0.125 / log(2.0));

  curve_attn_kernel<<<dim3(BH_N * (S_LEN / BQ)), dim3(256), 0, stream>>>(
      Q, K, V, O, W, sc_l2e, neg_l2C);
}